// Round 6
// baseline (315.499 us; speedup 1.0000x reference)
//
#include <hip/hip_runtime.h>
#include <stdint.h>

#define B_ 2
#define T_ 2048
#define C_ 2048
#define H_ 16
#define D_ 128
#define W_ 512
#define M_ (B_*T_)      // 4096
#define N1_ (3*C_)      // 6144

typedef short bf16x8 __attribute__((ext_vector_type(8)));
typedef unsigned short u16x8 __attribute__((ext_vector_type(8)));
typedef float f32x4 __attribute__((ext_vector_type(4)));

#define SB() __builtin_amdgcn_sched_barrier(0)

__device__ __forceinline__ unsigned short f2bf(float f) {
  union { float f; unsigned u; } v; v.f = f;
  unsigned r = v.u + 0x7fffu + ((v.u >> 16) & 1u);
  return (unsigned short)(r >> 16);
}
__device__ __forceinline__ float bf2f(unsigned short b) {
  union { unsigned u; float f; } v; v.u = ((unsigned)b) << 16;
  return v.f;
}

__device__ __forceinline__ void gload_lds16(const void* g, void* l) {
  __builtin_amdgcn_global_load_lds((const __attribute__((address_space(1))) void*)g,
                                   (__attribute__((address_space(3))) void*)l, 16, 0, 0);
}

// ---------- fp32 -> bf16 convert ----------
__global__ void k_cvt(const float* __restrict__ s, unsigned short* __restrict__ d, int n) {
  int i = (blockIdx.x * blockDim.x + threadIdx.x) * 8;
  if (i >= n) return;
  float4 a = *(const float4*)(s + i);
  float4 b = *(const float4*)(s + i + 4);
  u16x8 o;
  o[0]=f2bf(a.x); o[1]=f2bf(a.y); o[2]=f2bf(a.z); o[3]=f2bf(a.w);
  o[4]=f2bf(b.x); o[5]=f2bf(b.y); o[6]=f2bf(b.z); o[7]=f2bf(b.w);
  *(u16x8*)(d + i) = o;
}

// ---------- transpose + convert: src [R][Cc] f32 -> dst [Cc][R] bf16 ----------
__global__ void k_tcvt(const float* __restrict__ s, unsigned short* __restrict__ d, int R, int Cc) {
  __shared__ float tile[32][33];
  int c0 = blockIdx.x * 32, r0 = blockIdx.y * 32;
  int tx = threadIdx.x & 31, ty = threadIdx.x >> 5;
  #pragma unroll
  for (int j = 0; j < 32; j += 8) tile[ty + j][tx] = s[(size_t)(r0 + ty + j) * Cc + c0 + tx];
  __syncthreads();
  #pragma unroll
  for (int j = 0; j < 32; j += 8) d[(size_t)(c0 + ty + j) * R + r0 + tx] = f2bf(tile[tx][ty + j]);
}

// ---------- 256xBN GEMM, read-ahead-1-phase operand pipeline ----------
// LDS [parity][khalf][rows x 32k] bf16, st_16x32 swizzle. Per tile 4 phases:
//  C0: MFMA(P,X)->acc03 | read Q<-A[p][0]r47        | stage A(t+1)kh1
//  C1: MFMA(Q,X)->acc47 | read P<-A[p][1]r03,Y<-B[p][1] | stage B(t+2)kh0
//  C2: MFMA(P,Y)->acc03 | read Q<-A[p][1]r47,X<-B[p^1][0] | stage A(t+2)kh0
//  C3: MFMA(Q,Y)->acc47 | read P<-A[p^1][0]r03      | stage B(t+2)kh1
// Reads at phase START (pre-cluster) into regs disjoint from the cluster's
// operands -> LDS drain overlaps MFMA; lgkm(0) at next phase ~free.
// vmcnt (cross-wave safe: every-wave drain in a phase BEFORE the read, barrier
// between): C0 vmcnt(V0) drains {B(t)kh1,A(t)kh1} (read C1); C1 vmcnt(V1)
// drains {B(t+1)kh0,A(t+1)kh0} (read C2/C3/C0'); tail t>=NT-2 -> vmcnt(0).
template<int ROWS>
__device__ __forceinline__ void stage_half(const unsigned short* __restrict__ gbase,
                                           int row0, int K, int kt, int kh,
                                           unsigned short* region, int tid, int sw) {
  const char* gsrc = (const char*)(gbase + (size_t)row0 * K + kt * 64 + kh * 32);
  {
    int o = tid * 16, s = o ^ sw;
    gload_lds16(gsrc + (size_t)(s >> 6) * (K * 2) + (s & 63), (char*)region + o);
  }
  if (ROWS == 256) {
    int o = (512 + tid) * 16, s = o ^ sw;
    gload_lds16(gsrc + (size_t)(s >> 6) * (K * 2) + (s & 63), (char*)region + o);
  }
}

template<int BN, bool F32OUT>
__global__ __launch_bounds__(512, 2) void k_gemm8(const unsigned short* __restrict__ A,
                                                  const unsigned short* __restrict__ Bt,
                                                  void* __restrict__ Cp,
                                                  int Ntot, int K) {
  constexpr int NBF = BN / 64;
  constexpr int BROWS = (BN == 256) ? 256 : 128;
  constexpr int V0 = (BN == 256) ? 6 : 4;
  constexpr int V1 = (BN == 256) ? 4 : 3;
  __shared__ unsigned short As[2][2][256 * 32];
  __shared__ unsigned short Bs[2][2][BN * 32];
  const int tid = threadIdx.x, lane = tid & 63, wv = tid >> 6;
  const int wm = wv >> 2, wn = wv & 3;
  const int lr = lane & 15, lg = lane >> 4;
  const int sw = tid & 32;
  const int fofs = lr * 64 + ((lg * 16) ^ ((lr & 8) << 2));
  const int aoff = wm * 128 * 64 + fofs;
  const int boff = wn * (BN / 4) * 64 + fofs;

  const int nwg = gridDim.x;
  const int nbx = Ntot / BN;
  const int q = nwg >> 3, r = nwg & 7;
  const int xcd = blockIdx.x & 7, off = blockIdx.x >> 3;
  const int bid = (xcd < r ? xcd * (q + 1) : r * (q + 1) + (xcd - r) * q) + off;
  const int bm0 = (bid / nbx) << 8;
  const int bn0 = (bid % nbx) * BN;

  f32x4 acc[8][NBF];
  #pragma unroll
  for (int i = 0; i < 8; ++i)
    #pragma unroll
    for (int j = 0; j < NBF; ++j)
      #pragma unroll
      for (int e = 0; e < 4; ++e) acc[i][j][e] = 0.f;

  const int NT = K >> 6;

  // prologue: A0kh0,B0kh0 | B0kh1,A0kh1,B1kh0,A1kh0,B1kh1 ; drain first 2 halves
  stage_half<256  >(A,  bm0, K, 0, 0, As[0][0], tid, sw);
  stage_half<BROWS>(Bt, bn0, K, 0, 0, Bs[0][0], tid, sw);
  stage_half<BROWS>(Bt, bn0, K, 0, 1, Bs[0][1], tid, sw);
  stage_half<256  >(A,  bm0, K, 0, 1, As[0][1], tid, sw);
  stage_half<BROWS>(Bt, bn0, K, 1, 0, Bs[1][0], tid, sw);
  stage_half<256  >(A,  bm0, K, 1, 0, As[1][0], tid, sw);
  stage_half<BROWS>(Bt, bn0, K, 1, 1, Bs[1][1], tid, sw);
  if (BN == 256) asm volatile("s_waitcnt vmcnt(10)" ::: "memory");
  else           asm volatile("s_waitcnt vmcnt(7)"  ::: "memory");
  __builtin_amdgcn_s_barrier();

  bf16x8 Pf[4], Qf[4], Xf[NBF], Yf[NBF];
  #pragma unroll
  for (int i = 0; i < 4; ++i) Pf[i] = *(const bf16x8*)((const char*)As[0][0] + aoff + i * 1024);
  #pragma unroll
  for (int j = 0; j < NBF; ++j) Xf[j] = *(const bf16x8*)((const char*)Bs[0][0] + boff + j * 1024);

  #pragma unroll 2
  for (int t = 0; t < NT; ++t) {
    const int p = t & 1;
    const char* Ar0 = (const char*)As[p][0];
    const char* Ar1 = (const char*)As[p][1];
    const char* Br1 = (const char*)Bs[p][1];
    const char* ArN = (const char*)As[p ^ 1][0];
    const char* BrN = (const char*)Bs[p ^ 1][0];

    // ---- C0 ----
    asm volatile("s_waitcnt lgkmcnt(0)" ::: "memory"); SB();
    if (t < NT - 2) { if (BN==256) asm volatile("s_waitcnt vmcnt(6)" ::: "memory");
                      else         asm volatile("s_waitcnt vmcnt(4)" ::: "memory"); }
    else            asm volatile("s_waitcnt vmcnt(0)" ::: "memory");
    SB();
    #pragma unroll
    for (int i = 0; i < 4; ++i) Qf[i] = *(const bf16x8*)(Ar0 + aoff + (i + 4) * 1024);
    SB();
    __builtin_amdgcn_s_setprio(1);
    #pragma unroll
    for (int i = 0; i < 4; ++i)
      #pragma unroll
      for (int j = 0; j < NBF; ++j)
        acc[i][j] = __builtin_amdgcn_mfma_f32_16x16x32_bf16(Pf[i], Xf[j], acc[i][j], 0, 0, 0);
    __builtin_amdgcn_s_setprio(0);
    if (t + 1 < NT) stage_half<256>(A, bm0, K, t + 1, 1, As[p ^ 1][1], tid, sw);
    __builtin_amdgcn_s_barrier();

    // ---- C1 ----
    asm volatile("s_waitcnt lgkmcnt(0)" ::: "memory"); SB();
    if (t < NT - 2) { if (BN==256) asm volatile("s_waitcnt vmcnt(4)" ::: "memory");
                      else         asm volatile("s_waitcnt vmcnt(3)" ::: "memory"); }
    else            asm volatile("s_waitcnt vmcnt(0)" ::: "memory");
    SB();
    #pragma unroll
    for (int i = 0; i < 4; ++i) Pf[i] = *(const bf16x8*)(Ar1 + aoff + i * 1024);
    #pragma unroll
    for (int j = 0; j < NBF; ++j) Yf[j] = *(const bf16x8*)(Br1 + boff + j * 1024);
    SB();
    __builtin_amdgcn_s_setprio(1);
    #pragma unroll
    for (int i = 0; i < 4; ++i)
      #pragma unroll
      for (int j = 0; j < NBF; ++j)
        acc[i + 4][j] = __builtin_amdgcn_mfma_f32_16x16x32_bf16(Qf[i], Xf[j], acc[i + 4][j], 0, 0, 0);
    __builtin_amdgcn_s_setprio(0);
    if (t + 2 < NT) stage_half<BROWS>(Bt, bn0, K, t + 2, 0, Bs[p][0], tid, sw);
    __builtin_amdgcn_s_barrier();

    // ---- C2 ----
    asm volatile("s_waitcnt lgkmcnt(0)" ::: "memory"); SB();
    #pragma unroll
    for (int i = 0; i < 4; ++i) Qf[i] = *(const bf16x8*)(Ar1 + aoff + (i + 4) * 1024);
    if (t + 1 < NT) {
      #pragma unroll
      for (int j = 0; j < NBF; ++j) Xf[j] = *(const bf16x8*)(BrN + boff + j * 1024);
    }
    SB();
    __builtin_amdgcn_s_setprio(1);
    #pragma unroll
    for (int i = 0; i < 4; ++i)
      #pragma unroll
      for (int j = 0; j < NBF; ++j)
        acc[i][j] = __builtin_amdgcn_mfma_f32_16x16x32_bf16(Pf[i], Yf[j], acc[i][j], 0, 0, 0);
    __builtin_amdgcn_s_setprio(0);
    if (t + 2 < NT) stage_half<256>(A, bm0, K, t + 2, 0, As[p][0], tid, sw);
    __builtin_amdgcn_s_barrier();

    // ---- C3 ----
    asm volatile("s_waitcnt lgkmcnt(0)" ::: "memory"); SB();
    if (t + 1 < NT) {
      #pragma unroll
      for (int i = 0; i < 4; ++i) Pf[i] = *(const bf16x8*)(ArN + aoff + i * 1024);
    }
    SB();
    __builtin_amdgcn_s_setprio(1);
    #pragma unroll
    for (int i = 0; i < 4; ++i)
      #pragma unroll
      for (int j = 0; j < NBF; ++j)
        acc[i + 4][j] = __builtin_amdgcn_mfma_f32_16x16x32_bf16(Qf[i], Yf[j], acc[i + 4][j], 0, 0, 0);
    __builtin_amdgcn_s_setprio(0);
    if (t + 2 < NT) stage_half<BROWS>(Bt, bn0, K, t + 2, 1, Bs[p][1], tid, sw);
    __builtin_amdgcn_s_barrier();
  }
  asm volatile("s_waitcnt lgkmcnt(0)" ::: "memory");

  #pragma unroll
  for (int i = 0; i < 8; ++i)
    #pragma unroll
    for (int j = 0; j < NBF; ++j) {
      int m = bm0 + wm * 128 + i * 16 + lg * 4;
      int n = bn0 + wn * (BN / 4) + j * 16 + lr;
      #pragma unroll
      for (int e = 0; e < 4; ++e) {
        if (F32OUT) ((float*)Cp)[(size_t)(m + e) * Ntot + n] = acc[i][j][e];
        else ((unsigned short*)Cp)[(size_t)(m + e) * Ntot + n] = f2bf(acc[i][j][e]);
      }
    }
}

// ---------- reorg: RoPE(q,k) -> (B,H,T,D); v -> v_t (B,H,D,T) ----------
__global__ __launch_bounds__(256) void k_reorg(const unsigned short* __restrict__ qkv,
                        const float* __restrict__ fcos, const float* __restrict__ fsin,
                        unsigned short* __restrict__ q_r, unsigned short* __restrict__ k_r,
                        unsigned short* __restrict__ v_t) {
  const int bh = blockIdx.x, b = bh >> 4, h = bh & 15;
  const int t0 = blockIdx.y * 64;
  const int tid = threadIdx.x;
  __shared__ unsigned short vt[64][136];
  #pragma unroll
  for (int p = 0; p < 4; ++p) {
    int idx = p * 256 + tid;
    int tl = idx >> 4, sg = idx & 15;
    int t = t0 + tl, d0 = sg * 8;
    float sgn = (d0 < 64) ? -1.f : 1.f;
    float4 c0v = *(const float4*)(fcos + t * D_ + d0);
    float4 c1v = *(const float4*)(fcos + t * D_ + d0 + 4);
    float4 s0v = *(const float4*)(fsin + t * D_ + d0);
    float4 s1v = *(const float4*)(fsin + t * D_ + d0 + 4);
    float cs[8] = {c0v.x,c0v.y,c0v.z,c0v.w,c1v.x,c1v.y,c1v.z,c1v.w};
    float sn[8] = {s0v.x,s0v.y,s0v.z,s0v.w,s1v.x,s1v.y,s1v.z,s1v.w};
    #pragma unroll
    for (int w = 0; w < 2; ++w) {
      const unsigned short* src = qkv + (size_t)(b*T_ + t) * N1_ + w*C_ + h*D_;
      u16x8 a  = *(const u16x8*)(src + d0);
      u16x8 pr = *(const u16x8*)(src + (d0 ^ 64));
      u16x8 o;
      #pragma unroll
      for (int e = 0; e < 8; ++e)
        o[e] = f2bf(bf2f(a[e]) * cs[e] + sgn * bf2f(pr[e]) * sn[e]);
      unsigned short* dst = (w ? k_r : q_r) + (size_t)((b*H_ + h)*T_ + t) * D_ + d0;
      *(u16x8*)dst = o;
    }
    const unsigned short* vsrc = qkv + (size_t)(b*T_ + t) * N1_ + 2*C_ + h*D_ + d0;
    *(u16x8*)&vt[tl][d0] = *(const u16x8*)vsrc;
  }
  __syncthreads();
  #pragma unroll
  for (int p = 0; p < 4; ++p) {
    int idx = p * 256 + tid;
    int sg = idx & 7, d = idx >> 3;
    u16x8 o;
    #pragma unroll
    for (int e = 0; e < 8; ++e) o[e] = vt[sg*8 + e][d];
    *(u16x8*)(v_t + (size_t)((b*H_ + h)*D_ + d) * T_ + t0 + sg*8) = o;
  }
}

// ---------- sliding-window flash attention: 8 waves, q=128/block ----------
// Swizzled LDS (no pads): Ks[64][16 blks] cb^=((row&7)<<1); Vs[128][8 blks]
// cb^=(d&7); Ps per-wave [16][8 blks] cb^=(row&7). All reads/writes 2-way max.
__global__ __launch_bounds__(512) void k_attn(const unsigned short* __restrict__ q_r,
                       const unsigned short* __restrict__ k_r,
                       const unsigned short* __restrict__ v_t,
                       unsigned short* __restrict__ y) {
  const int bh = blockIdx.x, b = bh >> 4, h = bh & 15;
  const int q0 = blockIdx.y * 128;
  const int tid = threadIdx.x, lane = tid & 63, wv = tid >> 6;
  const int lr = lane & 15, lg = lane >> 4;

  __shared__ unsigned short Ks[64 * 128];
  __shared__ unsigned short Vs[128 * 64];
  __shared__ unsigned short Ps[8 * 16 * 64];

  const size_t bhT = (size_t)(b*H_ + h) * T_;
  const size_t bhD = (size_t)(b*H_ + h) * D_;
  const unsigned short* qbase = q_r + (bhT + q0 + wv*16 + lr) * D_;
  bf16x8 qf[4];
  #pragma unroll
  for (int kk = 0; kk < 4; ++kk) qf[kk] = *(const bf16x8*)(qbase + kk*32 + lg*8);

  f32x4 o[8];
  #pragma unroll
  for (int i = 0; i < 8; ++i)
    #pragma unroll
    for (int e = 0; e < 4; ++e) o[i][e] = 0.f;
  float m_run[4], l_sum[4];
  #pragma unroll
  for (int e = 0; e < 4; ++e) { m_run[e] = -1e30f; l_sum[e] = 0.f; }

  const int i_min = q0 + wv*16, i_max = i_min + 15;
  int kt_lo = q0 - (W_ - 1); if (kt_lo < 0) kt_lo = 0; kt_lo &= ~63;
  const float scale = 0.08838834764831845f;

  unsigned short* Ps_w = Ps + wv * 1024;

  for (int kt = kt_lo; kt < q0 + 128; kt += 64) {
    #pragma unroll
    for (int c = 0; c < 2; ++c) {
      int idx = c*512 + tid;
      int row = idx >> 4, cb = idx & 15;
      int cbs = cb ^ ((row & 7) << 1);
      *(u16x8*)&Ks[row*128 + cbs*8] = *(const u16x8*)(k_r + (bhT + kt + row) * D_ + cb*8);
    }
    #pragma unroll
    for (int c = 0; c < 2; ++c) {
      int idx = c*512 + tid;
      int d = idx >> 3, sg = idx & 7;
      int cbs = sg ^ (d & 7);
      *(u16x8*)&Vs[d*64 + cbs*8] = *(const u16x8*)(v_t + (bhD + d) * T_ + kt + sg*8);
    }
    __syncthreads();

    if (kt <= i_max && kt + 63 >= i_min - (W_ - 1)) {
      f32x4 s[4];
      #pragma unroll
      for (int ct = 0; ct < 4; ++ct)
        #pragma unroll
        for (int e = 0; e < 4; ++e) s[ct][e] = 0.f;
      #pragma unroll
      for (int kk = 0; kk < 4; ++kk) {
        #pragma unroll
        for (int ct = 0; ct < 4; ++ct) {
          bf16x8 kf = *(const bf16x8*)&Ks[(ct*16 + lr)*128 + ((kk*4 + lg) ^ ((lr & 7) << 1))*8];
          s[ct] = __builtin_amdgcn_mfma_f32_16x16x32_bf16(qf[kk], kf, s[ct], 0, 0, 0);
        }
      }
      float sv[4][4], mnew[4];
      int grow = 0;
      #pragma unroll
      for (int e = 0; e < 4; ++e) {
        int i = i_min + lg*4 + e;
        float rm = -1e30f;
        #pragma unroll
        for (int ct = 0; ct < 4; ++ct) {
          int j = kt + ct*16 + lr;
          bool ok = (j <= i) && (j > i - W_);
          sv[e][ct] = ok ? s[ct][e] * scale : -1e30f;
          rm = fmaxf(rm, sv[e][ct]);
        }
        #pragma unroll
        for (int msk = 1; msk < 16; msk <<= 1) rm = fmaxf(rm, __shfl_xor(rm, msk));
        mnew[e] = fmaxf(m_run[e], rm);
        grow |= (mnew[e] > m_run[e]) ? 1 : 0;
      }
      if (__any(grow)) {
        #pragma unroll
        for (int e = 0; e < 4; ++e) {
          float fac = __expf(m_run[e] - mnew[e]);
          l_sum[e] *= fac;
          m_run[e] = mnew[e];
          #pragma unroll
          for (int nt = 0; nt < 8; ++nt) o[nt][e] *= fac;
        }
      }
      #pragma unroll
      for (int e = 0; e < 4; ++e) {
        int prow = lg*4 + e;
        float rs = 0.f;
        #pragma unroll
        for (int ct = 0; ct < 4; ++ct) {
          float pv = (sv[e][ct] > -1e29f) ? __expf(sv[e][ct] - m_run[e]) : 0.f;
          rs += pv;
          Ps_w[prow*64 + ((ct*2 + (lr >> 3)) ^ (prow & 7))*8 + (lr & 7)] = f2bf(pv);
        }
        #pragma unroll
        for (int msk = 1; msk < 16; msk <<= 1) rs += __shfl_xor(rs, msk);
        l_sum[e] += rs;
      }
      asm volatile("s_waitcnt lgkmcnt(0)" ::: "memory"); SB();
      #pragma unroll
      for (int kk = 0; kk < 2; ++kk) {
        bf16x8 pf = *(const bf16x8*)&Ps_w[lr*64 + ((kk*4 + lg) ^ (lr & 7))*8];
        #pragma unroll
        for (int nt = 0; nt < 8; ++nt) {
          bf16x8 vf = *(const bf16x8*)&Vs[(nt*16 + lr)*64 + ((kk*4 + lg) ^ (lr & 7))*8];
          o[nt] = __builtin_amdgcn_mfma_f32_16x16x32_bf16(pf, vf, o[nt], 0, 0, 0);
        }
      }
    }
    __syncthreads();
  }

  #pragma unroll
  for (int nt = 0; nt < 8; ++nt) {
    #pragma unroll
    for (int e = 0; e < 4; ++e) {
      int t = q0 + wv*16 + lg*4 + e;
      int d = nt*16 + lr;
      y[(size_t)(b*T_ + t) * C_ + h*D_ + d] = f2bf(o[nt][e] / l_sum[e]);
    }
  }
}

extern "C" void kernel_launch(void* const* d_in, const int* in_sizes, int n_in,
                              void* d_out, int out_size, void* d_ws, size_t ws_size,
                              hipStream_t stream) {
  const float* x      = (const float*)d_in[0];
  const float* fcos   = (const float*)d_in[1];
  const float* fsin   = (const float*)d_in[2];
  const float* w_attn = (const float*)d_in[3];
  const float* w_proj = (const float*)d_in[4];
  float* out = (float*)d_out;

  char* ws = (char*)d_ws;
  unsigned short* x_bf = (unsigned short*)(ws);
  unsigned short* wa_t = (unsigned short*)(ws + 16777216ull);
  unsigned short* wp_t = (unsigned short*)(ws + 41943040ull);
  unsigned short* qkv  = (unsigned short*)(ws + 50331648ull);
  unsigned short* q_r  = (unsigned short*)(ws + 100663296ull);
  unsigned short* k_r  = (unsigned short*)(ws + 117440512ull);
  unsigned short* v_t  = (unsigned short*)(ws + 134217728ull);
  unsigned short* y_bf = x_bf;

  k_cvt<<<dim3(4096), dim3(256), 0, stream>>>(x, x_bf, M_*C_);
  k_tcvt<<<dim3(192, 64), dim3(256), 0, stream>>>(w_attn, wa_t, C_, N1_);
  k_tcvt<<<dim3(64, 64), dim3(256), 0, stream>>>(w_proj, wp_t, C_, C_);
  k_gemm8<256, false><<<dim3(384), dim3(512), 0, stream>>>(x_bf, wa_t, qkv, N1_, C_);
  k_reorg<<<dim3(32, 32), dim3(256), 0, stream>>>(qkv, fcos, fsin, q_r, k_r, v_t);
  k_attn<<<dim3(32, 16), dim3(512), 0, stream>>>(q_r, k_r, v_t, y_bf);
  k_gemm8<128, true><<<dim3(256), dim3(512), 0, stream>>>(y_bf, wp_t, out, C_, C_);
}

// Round 8
// 299.310 us; speedup vs baseline: 1.0541x; 1.0541x over previous
//
#include <hip/hip_runtime.h>
#include <stdint.h>

#define B_ 2
#define T_ 2048
#define C_ 2048
#define H_ 16
#define D_ 128
#define W_ 512
#define M_ (B_*T_)      // 4096
#define N1_ (3*C_)      // 6144

typedef short bf16x8 __attribute__((ext_vector_type(8)));
typedef unsigned short u16x8 __attribute__((ext_vector_type(8)));
typedef float f32x4 __attribute__((ext_vector_type(4)));

#define SB() __builtin_amdgcn_sched_barrier(0)

__device__ __forceinline__ unsigned short f2bf(float f) {
  union { float f; unsigned u; } v; v.f = f;
  unsigned r = v.u + 0x7fffu + ((v.u >> 16) & 1u);
  return (unsigned short)(r >> 16);
}
__device__ __forceinline__ float bf2f(unsigned short b) {
  union { unsigned u; float f; } v; v.u = ((unsigned)b) << 16;
  return v.f;
}

__device__ __forceinline__ void gload_lds16(const void* g, void* l) {
  __builtin_amdgcn_global_load_lds((const __attribute__((address_space(1))) void*)g,
                                   (__attribute__((address_space(3))) void*)l, 16, 0, 0);
}

// ---------- fp32 -> bf16 convert ----------
__global__ void k_cvt(const float* __restrict__ s, unsigned short* __restrict__ d, int n) {
  int i = (blockIdx.x * blockDim.x + threadIdx.x) * 8;
  if (i >= n) return;
  float4 a = *(const float4*)(s + i);
  float4 b = *(const float4*)(s + i + 4);
  u16x8 o;
  o[0]=f2bf(a.x); o[1]=f2bf(a.y); o[2]=f2bf(a.z); o[3]=f2bf(a.w);
  o[4]=f2bf(b.x); o[5]=f2bf(b.y); o[6]=f2bf(b.z); o[7]=f2bf(b.w);
  *(u16x8*)(d + i) = o;
}

// ---------- transpose + convert: src [R][Cc] f32 -> dst [Cc][R] bf16 ----------
__global__ void k_tcvt(const float* __restrict__ s, unsigned short* __restrict__ d, int R, int Cc) {
  __shared__ float tile[32][33];
  int c0 = blockIdx.x * 32, r0 = blockIdx.y * 32;
  int tx = threadIdx.x & 31, ty = threadIdx.x >> 5;
  #pragma unroll
  for (int j = 0; j < 32; j += 8) tile[ty + j][tx] = s[(size_t)(r0 + ty + j) * Cc + c0 + tx];
  __syncthreads();
  #pragma unroll
  for (int j = 0; j < 32; j += 8) d[(size_t)(c0 + ty + j) * R + r0 + tx] = f2bf(tile[tx][ty + j]);
}

// ---------- shared staging helper: st_16x32 XOR swizzle, DMA direct ----------
template<int ROWS>
__device__ __forceinline__ void stage_half(const unsigned short* __restrict__ gbase,
                                           int row0, int K, int kt, int kh,
                                           unsigned short* region, int tid, int sw) {
  const char* gsrc = (const char*)(gbase + (size_t)row0 * K + kt * 64 + kh * 32);
  {
    int o = tid * 16, s = o ^ sw;
    gload_lds16(gsrc + (size_t)(s >> 6) * (K * 2) + (s & 63), (char*)region + o);
  }
  if (ROWS == 256) {
    int o = (512 + tid) * 16, s = o ^ sw;
    gload_lds16(gsrc + (size_t)(s >> 6) * (K * 2) + (s & 63), (char*)region + o);
  }
}

// ---------- GEMM1: 256x256, 4-phase, register-pipelined (R4 best) ----------
template<bool F32OUT>
__global__ __launch_bounds__(512, 2) void k_gemm8(const unsigned short* __restrict__ A,
                                                  const unsigned short* __restrict__ Bt,
                                                  void* __restrict__ Cp,
                                                  int Ntot, int K) {
  __shared__ unsigned short As[2][2][256 * 32];
  __shared__ unsigned short Bs[2][2][256 * 32];
  const int tid = threadIdx.x, lane = tid & 63, wv = tid >> 6;
  const int wm = wv >> 2, wn = wv & 3;
  const int lr = lane & 15, lg = lane >> 4;
  const int sw = tid & 32;
  const int fofs = lr * 64 + ((lg * 16) ^ ((lr & 8) << 2));
  const int aoff = wm * 128 * 64 + fofs;
  const int boff = wn * 64 * 64 + fofs;

  const int nwg = gridDim.x;
  const int nbx = Ntot >> 8;
  const int q = nwg >> 3, r = nwg & 7;
  const int xcd = blockIdx.x & 7, off = blockIdx.x >> 3;
  const int bid = (xcd < r ? xcd * (q + 1) : r * (q + 1) + (xcd - r) * q) + off;
  const int bm0 = (bid / nbx) << 8;
  const int bn0 = (bid % nbx) << 8;

  f32x4 acc[8][4];
  #pragma unroll
  for (int i = 0; i < 8; ++i)
    #pragma unroll
    for (int j = 0; j < 4; ++j)
      #pragma unroll
      for (int e = 0; e < 4; ++e) acc[i][j][e] = 0.f;

  const int NT = K >> 6;

  stage_half<256>(A,  bm0, K, 0, 0, As[0][0], tid, sw);
  stage_half<256>(Bt, bn0, K, 0, 0, Bs[0][0], tid, sw);
  stage_half<256>(Bt, bn0, K, 0, 1, Bs[0][1], tid, sw);
  stage_half<256>(A,  bm0, K, 0, 1, As[0][1], tid, sw);
  stage_half<256>(Bt, bn0, K, 1, 0, Bs[1][0], tid, sw);
  stage_half<256>(A,  bm0, K, 1, 0, As[1][0], tid, sw);
  stage_half<256>(Bt, bn0, K, 1, 1, Bs[1][1], tid, sw);
  asm volatile("s_waitcnt vmcnt(4)" ::: "memory");
  __builtin_amdgcn_s_barrier();

  bf16x8 Xa[4], Xb[4], Ya[4];
  #pragma unroll
  for (int j = 0; j < 4; ++j) Xb[j] = *(const bf16x8*)((const char*)Bs[0][0] + boff + j * 1024);
  #pragma unroll
  for (int i = 0; i < 4; ++i) Xa[i] = *(const bf16x8*)((const char*)As[0][0] + aoff + i * 1024);

  #pragma unroll 2
  for (int t = 0; t < NT; ++t) {
    const int p = t & 1;
    // ---- ph0: MFMA(acc0-3, Xa,Xb); load Ya=A[p][0]r4-7; stage (t+1).A1 ----
    asm volatile("s_waitcnt lgkmcnt(0)" ::: "memory");
    __builtin_amdgcn_sched_barrier(0);
    __builtin_amdgcn_s_setprio(1);
    #pragma unroll
    for (int i = 0; i < 4; ++i)
      #pragma unroll
      for (int j = 0; j < 4; ++j)
        acc[i][j] = __builtin_amdgcn_mfma_f32_16x16x32_bf16(Xa[i], Xb[j], acc[i][j], 0, 0, 0);
    __builtin_amdgcn_s_setprio(0);
    #pragma unroll
    for (int i = 0; i < 4; ++i) Ya[i] = *(const bf16x8*)((const char*)As[p][0] + aoff + (i + 4) * 1024);
    if (t + 1 < NT) stage_half<256>(A, bm0, K, t + 1, 1, As[p ^ 1][1], tid, sw);
    __builtin_amdgcn_s_barrier();

    // ---- ph1: MFMA(acc4-7, Ya,Xb); load Xb=B[p][1], Xa=A[p][1]r0-3; stage (t+2).B0 ----
    asm volatile("s_waitcnt lgkmcnt(0)" ::: "memory");
    __builtin_amdgcn_sched_barrier(0);
    __builtin_amdgcn_s_setprio(1);
    #pragma unroll
    for (int i = 0; i < 4; ++i)
      #pragma unroll
      for (int j = 0; j < 4; ++j)
        acc[i + 4][j] = __builtin_amdgcn_mfma_f32_16x16x32_bf16(Ya[i], Xb[j], acc[i + 4][j], 0, 0, 0);
    __builtin_amdgcn_s_setprio(0);
    #pragma unroll
    for (int j = 0; j < 4; ++j) Xb[j] = *(const bf16x8*)((const char*)Bs[p][1] + boff + j * 1024);
    #pragma unroll
    for (int i = 0; i < 4; ++i) Xa[i] = *(const bf16x8*)((const char*)As[p][1] + aoff + i * 1024);
    if (t + 2 < NT) stage_half<256>(Bt, bn0, K, t + 2, 0, Bs[p][0], tid, sw);
    __builtin_amdgcn_s_barrier();

    // ---- ph2: MFMA(acc0-3, Xa,Xb); load Ya=A[p][1]r4-7; stage (t+2).A0 ----
    asm volatile("s_waitcnt lgkmcnt(0)" ::: "memory");
    __builtin_amdgcn_sched_barrier(0);
    __builtin_amdgcn_s_setprio(1);
    #pragma unroll
    for (int i = 0; i < 4; ++i)
      #pragma unroll
      for (int j = 0; j < 4; ++j)
        acc[i][j] = __builtin_amdgcn_mfma_f32_16x16x32_bf16(Xa[i], Xb[j], acc[i][j], 0, 0, 0);
    __builtin_amdgcn_s_setprio(0);
    #pragma unroll
    for (int i = 0; i < 4; ++i) Ya[i] = *(const bf16x8*)((const char*)As[p][1] + aoff + (i + 4) * 1024);
    if (t + 2 < NT) stage_half<256>(A, bm0, K, t + 2, 0, As[p][0], tid, sw);
    __builtin_amdgcn_s_barrier();

    // ---- ph3: MFMA(acc4-7, Ya,Xb); vmcnt; load next-tile X; stage (t+2).B1 ----
    asm volatile("s_waitcnt lgkmcnt(0)" ::: "memory");
    __builtin_amdgcn_sched_barrier(0);
    __builtin_amdgcn_s_setprio(1);
    #pragma unroll
    for (int i = 0; i < 4; ++i)
      #pragma unroll
      for (int j = 0; j < 4; ++j)
        acc[i + 4][j] = __builtin_amdgcn_mfma_f32_16x16x32_bf16(Ya[i], Xb[j], acc[i + 4][j], 0, 0, 0);
    __builtin_amdgcn_s_setprio(0);
    if (t < NT - 2) asm volatile("s_waitcnt vmcnt(4)" ::: "memory");
    else            asm volatile("s_waitcnt vmcnt(0)" ::: "memory");
    #pragma unroll
    for (int j = 0; j < 4; ++j) Xb[j] = *(const bf16x8*)((const char*)Bs[p ^ 1][0] + boff + j * 1024);
    #pragma unroll
    for (int i = 0; i < 4; ++i) Xa[i] = *(const bf16x8*)((const char*)As[p ^ 1][0] + aoff + i * 1024);
    if (t + 2 < NT) stage_half<256>(Bt, bn0, K, t + 2, 1, Bs[p][1], tid, sw);
    __builtin_amdgcn_s_barrier();
  }
  asm volatile("s_waitcnt lgkmcnt(0)" ::: "memory");

  #pragma unroll
  for (int i = 0; i < 8; ++i)
    #pragma unroll
    for (int j = 0; j < 4; ++j) {
      int m = bm0 + wm * 128 + i * 16 + lg * 4;
      int n = bn0 + wn * 64 + j * 16 + lr;
      #pragma unroll
      for (int e = 0; e < 4; ++e) {
        if (F32OUT) ((float*)Cp)[(size_t)(m + e) * Ntot + n] = acc[i][j][e];
        else ((unsigned short*)Cp)[(size_t)(m + e) * Ntot + n] = f2bf(acc[i][j][e]);
      }
    }
}

// ---------- GEMM2: 128x256 tile, 2 phases/tile, grid = 1 exact round ----------
// 8 waves own 64x64 each (acc 4x4). ph0: MFMA(kh0 via P,X) | read Q,Y=kh1 |
// stage (t+1)kh1. ph1: MFMA(kh1 via Q,Y) | read P,X=(t+1)kh0 | stage (t+2)kh0.
// CROSS-WAVE RULE (round-7 bug fix): every ds_read's producing DMA group must
// be drained by an every-wave vmcnt in an EARLIER phase with a barrier in
// between. Prologue now: stages -> vmcnt(3) [drains t0k0+t0k1 on all waves]
// -> barrier -> preload. Loop ledger (verified): ph0 reads t.k1 (drained
// (t-1).ph1 vmcnt(3)+barrier); ph1 reads (t+1).k0 (drained t.ph0
// vmcnt(3)+barrier). DMA WAR: each stage target's readers drained >=1 phase
// earlier by lgkm(0)+barrier. Tail t>=NT-2: vmcnt(0).
__global__ __launch_bounds__(512, 2) void k_gemmB(const unsigned short* __restrict__ A,
                                                  const unsigned short* __restrict__ Bt,
                                                  float* __restrict__ Cp,
                                                  int Ntot, int K) {
  __shared__ unsigned short As[2][2][128 * 32];
  __shared__ unsigned short Bs[2][2][256 * 32];
  const int tid = threadIdx.x, lane = tid & 63, wv = tid >> 6;
  const int wm = wv >> 2, wn = wv & 3;
  const int lr = lane & 15, lg = lane >> 4;
  const int sw = tid & 32;
  const int fofs = lr * 64 + ((lg * 16) ^ ((lr & 8) << 2));
  const int aoff = wm * 64 * 64 + fofs;
  const int boff = wn * 64 * 64 + fofs;

  const int nwg = gridDim.x;
  const int nbx = Ntot >> 8;
  const int q = nwg >> 3, r = nwg & 7;
  const int xcd = blockIdx.x & 7, off = blockIdx.x >> 3;
  const int bid = (xcd < r ? xcd * (q + 1) : r * (q + 1) + (xcd - r) * q) + off;
  const int bm0 = (bid / nbx) * 128;
  const int bn0 = (bid % nbx) << 8;

  f32x4 acc[4][4];
  #pragma unroll
  for (int i = 0; i < 4; ++i)
    #pragma unroll
    for (int j = 0; j < 4; ++j)
      #pragma unroll
      for (int e = 0; e < 4; ++e) acc[i][j][e] = 0.f;

  const int NT = K >> 6;

  // prologue: G1={t0k0}, G2={t0k1}, G3={t1k0} (3 ticks each: A=1, B=2)
  stage_half<128>(A,  bm0, K, 0, 0, As[0][0], tid, sw);
  stage_half<256>(Bt, bn0, K, 0, 0, Bs[0][0], tid, sw);
  stage_half<128>(A,  bm0, K, 0, 1, As[0][1], tid, sw);
  stage_half<256>(Bt, bn0, K, 0, 1, Bs[0][1], tid, sw);
  stage_half<128>(A,  bm0, K, 1, 0, As[1][0], tid, sw);
  stage_half<256>(Bt, bn0, K, 1, 0, Bs[1][0], tid, sw);
  asm volatile("s_waitcnt vmcnt(3)" ::: "memory");   // t0k0 + t0k1 done (every wave)
  __builtin_amdgcn_s_barrier();                      // publish before ANY read
  bf16x8 Pf[4], Qf[4], Xf[4], Yf[4];
  #pragma unroll
  for (int i = 0; i < 4; ++i) Pf[i] = *(const bf16x8*)((const char*)As[0][0] + aoff + i * 1024);
  #pragma unroll
  for (int j = 0; j < 4; ++j) Xf[j] = *(const bf16x8*)((const char*)Bs[0][0] + boff + j * 1024);

  #pragma unroll 2
  for (int t = 0; t < NT; ++t) {
    const int p = t & 1;
    // ---- ph0 ----
    asm volatile("s_waitcnt lgkmcnt(0)" ::: "memory");
    __builtin_amdgcn_sched_barrier(0);
    __builtin_amdgcn_s_setprio(1);
    #pragma unroll
    for (int i = 0; i < 4; ++i)
      #pragma unroll
      for (int j = 0; j < 4; ++j)
        acc[i][j] = __builtin_amdgcn_mfma_f32_16x16x32_bf16(Pf[i], Xf[j], acc[i][j], 0, 0, 0);
    __builtin_amdgcn_s_setprio(0);
    #pragma unroll
    for (int i = 0; i < 4; ++i) Qf[i] = *(const bf16x8*)((const char*)As[p][1] + aoff + i * 1024);
    #pragma unroll
    for (int j = 0; j < 4; ++j) Yf[j] = *(const bf16x8*)((const char*)Bs[p][1] + boff + j * 1024);
    if (t + 1 < NT) {
      stage_half<128>(A,  bm0, K, t + 1, 1, As[p ^ 1][1], tid, sw);
      stage_half<256>(Bt, bn0, K, t + 1, 1, Bs[p ^ 1][1], tid, sw);
    }
    if (t < NT - 2) asm volatile("s_waitcnt vmcnt(3)" ::: "memory");
    else            asm volatile("s_waitcnt vmcnt(0)" ::: "memory");
    __builtin_amdgcn_s_barrier();

    // ---- ph1 ----
    asm volatile("s_waitcnt lgkmcnt(0)" ::: "memory");
    __builtin_amdgcn_sched_barrier(0);
    __builtin_amdgcn_s_setprio(1);
    #pragma unroll
    for (int i = 0; i < 4; ++i)
      #pragma unroll
      for (int j = 0; j < 4; ++j)
        acc[i][j] = __builtin_amdgcn_mfma_f32_16x16x32_bf16(Qf[i], Yf[j], acc[i][j], 0, 0, 0);
    __builtin_amdgcn_s_setprio(0);
    if (t + 1 < NT) {
      #pragma unroll
      for (int i = 0; i < 4; ++i) Pf[i] = *(const bf16x8*)((const char*)As[p ^ 1][0] + aoff + i * 1024);
      #pragma unroll
      for (int j = 0; j < 4; ++j) Xf[j] = *(const bf16x8*)((const char*)Bs[p ^ 1][0] + boff + j * 1024);
    }
    if (t + 2 < NT) {
      stage_half<128>(A,  bm0, K, t + 2, 0, As[p][0], tid, sw);
      stage_half<256>(Bt, bn0, K, t + 2, 0, Bs[p][0], tid, sw);
    }
    if (t < NT - 2) asm volatile("s_waitcnt vmcnt(3)" ::: "memory");
    else            asm volatile("s_waitcnt vmcnt(0)" ::: "memory");
    __builtin_amdgcn_s_barrier();
  }
  asm volatile("s_waitcnt lgkmcnt(0)" ::: "memory");

  #pragma unroll
  for (int i = 0; i < 4; ++i)
    #pragma unroll
    for (int j = 0; j < 4; ++j) {
      int m = bm0 + wm * 64 + i * 16 + lg * 4;
      int n = bn0 + wn * 64 + j * 16 + lr;
      #pragma unroll
      for (int e = 0; e < 4; ++e)
        Cp[(size_t)(m + e) * Ntot + n] = acc[i][j][e];
    }
}

// ---------- reorg: RoPE(q,k) -> (B,H,T,D); v -> v_t (B,H,D,T) ----------
__global__ __launch_bounds__(256) void k_reorg(const unsigned short* __restrict__ qkv,
                        const float* __restrict__ fcos, const float* __restrict__ fsin,
                        unsigned short* __restrict__ q_r, unsigned short* __restrict__ k_r,
                        unsigned short* __restrict__ v_t) {
  const int bh = blockIdx.x, b = bh >> 4, h = bh & 15;
  const int t0 = blockIdx.y * 64;
  const int tid = threadIdx.x;
  __shared__ unsigned short vt[64][136];
  #pragma unroll
  for (int p = 0; p < 4; ++p) {
    int idx = p * 256 + tid;
    int tl = idx >> 4, sg = idx & 15;
    int t = t0 + tl, d0 = sg * 8;
    float sgn = (d0 < 64) ? -1.f : 1.f;
    float4 c0v = *(const float4*)(fcos + t * D_ + d0);
    float4 c1v = *(const float4*)(fcos + t * D_ + d0 + 4);
    float4 s0v = *(const float4*)(fsin + t * D_ + d0);
    float4 s1v = *(const float4*)(fsin + t * D_ + d0 + 4);
    float cs[8] = {c0v.x,c0v.y,c0v.z,c0v.w,c1v.x,c1v.y,c1v.z,c1v.w};
    float sn[8] = {s0v.x,s0v.y,s0v.z,s0v.w,s1v.x,s1v.y,s1v.z,s1v.w};
    #pragma unroll
    for (int w = 0; w < 2; ++w) {
      const unsigned short* src = qkv + (size_t)(b*T_ + t) * N1_ + w*C_ + h*D_;
      u16x8 a  = *(const u16x8*)(src + d0);
      u16x8 pr = *(const u16x8*)(src + (d0 ^ 64));
      u16x8 o;
      #pragma unroll
      for (int e = 0; e < 8; ++e)
        o[e] = f2bf(bf2f(a[e]) * cs[e] + sgn * bf2f(pr[e]) * sn[e]);
      unsigned short* dst = (w ? k_r : q_r) + (size_t)((b*H_ + h)*T_ + t) * D_ + d0;
      *(u16x8*)dst = o;
    }
    const unsigned short* vsrc = qkv + (size_t)(b*T_ + t) * N1_ + 2*C_ + h*D_ + d0;
    *(u16x8*)&vt[tl][d0] = *(const u16x8*)vsrc;
  }
  __syncthreads();
  #pragma unroll
  for (int p = 0; p < 4; ++p) {
    int idx = p * 256 + tid;
    int sg = idx & 7, d = idx >> 3;
    u16x8 o;
    #pragma unroll
    for (int e = 0; e < 8; ++e) o[e] = vt[sg*8 + e][d];
    *(u16x8*)(v_t + (size_t)((b*H_ + h)*D_ + d) * T_ + t0 + sg*8) = o;
  }
}

// ---------- sliding-window flash attention: 8 waves, q=128/block ----------
__global__ __launch_bounds__(512) void k_attn(const unsigned short* __restrict__ q_r,
                       const unsigned short* __restrict__ k_r,
                       const unsigned short* __restrict__ v_t,
                       unsigned short* __restrict__ y) {
  const int bh = blockIdx.x, b = bh >> 4, h = bh & 15;
  const int q0 = blockIdx.y * 128;
  const int tid = threadIdx.x, lane = tid & 63, wv = tid >> 6;
  const int lr = lane & 15, lg = lane >> 4;

  __shared__ unsigned short Ks[64 * 128];
  __shared__ unsigned short Vs[128 * 64];
  __shared__ unsigned short Ps[8 * 16 * 64];

  const size_t bhT = (size_t)(b*H_ + h) * T_;
  const size_t bhD = (size_t)(b*H_ + h) * D_;
  const unsigned short* qbase = q_r + (bhT + q0 + wv*16 + lr) * D_;
  bf16x8 qf[4];
  #pragma unroll
  for (int kk = 0; kk < 4; ++kk) qf[kk] = *(const bf16x8*)(qbase + kk*32 + lg*8);

  f32x4 o[8];
  #pragma unroll
  for (int i = 0; i < 8; ++i)
    #pragma unroll
    for (int e = 0; e < 4; ++e) o[i][e] = 0.f;
  float m_run[4], l_sum[4];
  #pragma unroll
  for (int e = 0; e < 4; ++e) { m_run[e] = -1e30f; l_sum[e] = 0.f; }

  const int i_min = q0 + wv*16, i_max = i_min + 15;
  int kt_lo = q0 - (W_ - 1); if (kt_lo < 0) kt_lo = 0; kt_lo &= ~63;
  const float scale = 0.08838834764831845f;

  unsigned short* Ps_w = Ps + wv * 1024;

  for (int kt = kt_lo; kt < q0 + 128; kt += 64) {
    #pragma unroll
    for (int c = 0; c < 2; ++c) {
      int idx = c*512 + tid;
      int row = idx >> 4, cb = idx & 15;
      int cbs = cb ^ ((row & 7) << 1);
      *(u16x8*)&Ks[row*128 + cbs*8] = *(const u16x8*)(k_r + (bhT + kt + row) * D_ + cb*8);
    }
    #pragma unroll
    for (int c = 0; c < 2; ++c) {
      int idx = c*512 + tid;
      int d = idx >> 3, sg = idx & 7;
      int cbs = sg ^ (d & 7);
      *(u16x8*)&Vs[d*64 + cbs*8] = *(const u16x8*)(v_t + (bhD + d) * T_ + kt + sg*8);
    }
    __syncthreads();

    if (kt <= i_max && kt + 63 >= i_min - (W_ - 1)) {
      f32x4 s[4];
      #pragma unroll
      for (int ct = 0; ct < 4; ++ct)
        #pragma unroll
        for (int e = 0; e < 4; ++e) s[ct][e] = 0.f;
      #pragma unroll
      for (int kk = 0; kk < 4; ++kk) {
        #pragma unroll
        for (int ct = 0; ct < 4; ++ct) {
          bf16x8 kf = *(const bf16x8*)&Ks[(ct*16 + lr)*128 + ((kk*4 + lg) ^ ((lr & 7) << 1))*8];
          s[ct] = __builtin_amdgcn_mfma_f32_16x16x32_bf16(qf[kk], kf, s[ct], 0, 0, 0);
        }
      }
      float sv[4][4], mnew[4];
      int grow = 0;
      #pragma unroll
      for (int e = 0; e < 4; ++e) {
        int i = i_min + lg*4 + e;
        float rm = -1e30f;
        #pragma unroll
        for (int ct = 0; ct < 4; ++ct) {
          int j = kt + ct*16 + lr;
          bool ok = (j <= i) && (j > i - W_);
          sv[e][ct] = ok ? s[ct][e] * scale : -1e30f;
          rm = fmaxf(rm, sv[e][ct]);
        }
        #pragma unroll
        for (int msk = 1; msk < 16; msk <<= 1) rm = fmaxf(rm, __shfl_xor(rm, msk));
        mnew[e] = fmaxf(m_run[e], rm);
        grow |= (mnew[e] > m_run[e]) ? 1 : 0;
      }
      if (__any(grow)) {
        #pragma unroll
        for (int e = 0; e < 4; ++e) {
          float fac = __expf(m_run[e] - mnew[e]);
          l_sum[e] *= fac;
          m_run[e] = mnew[e];
          #pragma unroll
          for (int nt = 0; nt < 8; ++nt) o[nt][e] *= fac;
        }
      }
      #pragma unroll
      for (int e = 0; e < 4; ++e) {
        int prow = lg*4 + e;
        float rs = 0.f;
        #pragma unroll
        for (int ct = 0; ct < 4; ++ct) {
          float pv = (sv[e][ct] > -1e29f) ? __expf(sv[e][ct] - m_run[e]) : 0.f;
          rs += pv;
          Ps_w[prow*64 + ((ct*2 + (lr >> 3)) ^ (prow & 7))*8 + (lr & 7)] = f2bf(pv);
        }
        #pragma unroll
        for (int msk = 1; msk < 16; msk <<= 1) rs += __shfl_xor(rs, msk);
        l_sum[e] += rs;
      }
      asm volatile("s_waitcnt lgkmcnt(0)" ::: "memory"); SB();
      #pragma unroll
      for (int kk = 0; kk < 2; ++kk) {
        bf16x8 pf = *(const bf16x8*)&Ps_w[lr*64 + ((kk*4 + lg) ^ (lr & 7))*8];
        #pragma unroll
        for (int nt = 0; nt < 8; ++nt) {
          bf16x8 vf = *(const bf16x8*)&Vs[(nt*16 + lr)*64 + ((kk*4 + lg) ^ (lr & 7))*8];
          o[nt] = __builtin_amdgcn_mfma_f32_16x16x32_bf16(pf, vf, o[nt], 0, 0, 0);
        }
      }
    }
    __syncthreads();
  }

  #pragma unroll
  for (int nt = 0; nt < 8; ++nt) {
    #pragma unroll
    for (int e = 0; e < 4; ++e) {
      int t = q0 + wv*16 + lg*4 + e;
      int d = nt*16 + lr;
      y[(size_t)(b*T_ + t) * C_ + h*D_ + d] = f2bf(o[nt][e] / l_sum[e]);
    }
  }
}

extern "C" void kernel_launch(void* const* d_in, const int* in_sizes, int n_in,
                              void* d_out, int out_size, void* d_ws, size_t ws_size,
                              hipStream_t stream) {
  const float* x      = (const float*)d_in[0];
  const float* fcos   = (const float*)d_in[1];
  const float* fsin   = (const float*)d_in[2];
  const float* w_attn = (const float*)d_in[3];
  const float* w_proj = (const float*)d_in[4];
  float* out = (float*)d_out;

  char* ws = (char*)d_ws;
  unsigned short* x_bf = (unsigned short*)(ws);
  unsigned short* wa_t = (unsigned short*)(ws + 16777216ull);
  unsigned short* wp_t = (unsigned short*)(ws + 41943040ull);
  unsigned short* qkv  = (unsigned short*)(ws + 50331648ull);
  unsigned short* q_r  = (unsigned short*)(ws + 100663296ull);
  unsigned short* k_r  = (unsigned short*)(ws + 117440512ull);
  unsigned short* v_t  = (unsigned short*)(ws + 134217728ull);
  unsigned short* y_bf = x_bf;

  k_cvt<<<dim3(4096), dim3(256), 0, stream>>>(x, x_bf, M_*C_);
  k_tcvt<<<dim3(192, 64), dim3(256), 0, stream>>>(w_attn, wa_t, C_, N1_);
  k_tcvt<<<dim3(64, 64), dim3(256), 0, stream>>>(w_proj, wp_t, C_, C_);
  k_gemm8<false><<<dim3(384), dim3(512), 0, stream>>>(x_bf, wa_t, qkv, N1_, C_);
  k_reorg<<<dim3(32, 32), dim3(256), 0, stream>>>(qkv, fcos, fsin, q_r, k_r, v_t);
  k_attn<<<dim3(32, 16), dim3(512), 0, stream>>>(q_r, k_r, v_t, y_bf);
  k_gemmB<<<dim3(256), dim3(512), 0, stream>>>(y_bf, wp_t, out, C_, C_);
}